// Round 7
// baseline (268.079 us; speedup 1.0000x reference)
//
#include <hip/hip_runtime.h>

#define BS 4
#define SL 2048
#define NE 1024
#define NH 16
#define HD 64
#define N3 3072

typedef __attribute__((ext_vector_type(8))) __bf16 bf16x8;
typedef __attribute__((ext_vector_type(4))) float f32x4;
typedef __attribute__((ext_vector_type(4))) short s16x4;
typedef unsigned short u16;

__device__ __forceinline__ u16 f2bf(float f) {
  union { float f; unsigned int u; } v; v.f = f;
  unsigned int r = v.u + 0x7FFFu + ((v.u >> 16) & 1u);
  return (u16)(r >> 16);
}

// global -> LDS direct 16B copy. LDS dest is WAVE-UNIFORM base; HW adds
// lane*16. Global address is per-lane.
__device__ __forceinline__ void gld16(const void* g, void* l) {
#if __has_builtin(__builtin_amdgcn_global_load_lds)
  __builtin_amdgcn_global_load_lds(
      (const __attribute__((address_space(1))) unsigned int*)g,
      (__attribute__((address_space(3))) unsigned int*)l, 16, 0, 0);
#else
  *(int4*)((char*)l + (size_t)(threadIdx.x & 63) * 16) = *(const int4*)g;
#endif
}

// ---------------- x fp32 -> bf16 ----------------
__global__ void convert_x(const float* __restrict__ x, u16* __restrict__ xb) {
  int i = (blockIdx.x * 256 + threadIdx.x) * 8;
  float4 f0 = *(const float4*)(x + i);
  float4 f1 = *(const float4*)(x + i + 4);
  union { int4 v; u16 h[8]; } p;
  p.h[0] = f2bf(f0.x); p.h[1] = f2bf(f0.y);
  p.h[2] = f2bf(f0.z); p.h[3] = f2bf(f0.w);
  p.h[4] = f2bf(f1.x); p.h[5] = f2bf(f1.y);
  p.h[6] = f2bf(f1.z); p.h[7] = f2bf(f1.w);
  *(int4*)(xb + i) = p.v;
}

// ---------------- W transpose+convert: Wt[n*K+k] = bf16(W[k*N+n]) ----------
__global__ void transpose_w(const float* __restrict__ W, u16* __restrict__ Wt,
                            int K, int N) {
  __shared__ u16 tile[32][33];
  int bn = blockIdx.x * 32, bk = blockIdx.y * 32;
  int tx = threadIdx.x, ty = threadIdx.y;  // blockDim = (32, 8)
  for (int r = 0; r < 32; r += 8)
    tile[ty + r][tx] = f2bf(W[(size_t)(bk + ty + r) * N + bn + tx]);
  __syncthreads();
  for (int r = 0; r < 32; r += 8)
    Wt[(size_t)(bn + ty + r) * K + bk + tx] = tile[tx][ty + r];
}

// ============ loose 2-block/CU GEMM (unchanged from round 4) ============
#define MFMA_G(a, b, c) \
  __builtin_amdgcn_mfma_f32_16x16x32_bf16(a, b, c, 0, 0, 0)

template <int C32>
__global__ __launch_bounds__(256, 2) void gemm2b(
    const u16* __restrict__ A, const u16* __restrict__ Bt,
    const float* __restrict__ bias, void* __restrict__ C, int M, int N, int K,
    int lda) {
  constexpr int BM = 128, BN = 128, BK = 64;
  __shared__ u16 As[2][BM * BK];  // 16 KB each
  __shared__ u16 Bs[2][BN * BK];

  const int tid = threadIdx.x;
  const int w = tid >> 6, lane = tid & 63;
  const int lq = lane >> 4, lr = lane & 15;
  const int nwx = gridDim.x;
  const int nwg = nwx * gridDim.y;
  const int lin = blockIdx.y * nwx + blockIdx.x;
  const int cpx = nwg >> 3;
  const int swb = (lin & 7) * cpx + (lin >> 3);
  const int m0 = (swb / nwx) * BM, n0 = (swb % nwx) * BN;
  const int wm = (w >> 1) * 64, wn = (w & 1) * 64;

  const int l8 = lane >> 3, lb = lane & 7;
  const int sw8 = (lb ^ l8) * 8;  // elems
  const u16* gA = A + (size_t)(m0 + w * 32 + l8) * lda + sw8;
  const u16* gB = Bt + (size_t)(n0 + w * 32 + l8) * K + sw8;

#define STAGE(buf, gpa, gpb)                                  \
  do {                                                        \
    _Pragma("unroll") for (int c = 0; c < 4; c++) {           \
      gld16((gpa) + (size_t)(c * 8) * lda,                    \
            &As[buf][(w * 32 + c * 8) * 64]);                 \
      gld16((gpb) + (size_t)(c * 8) * K,                      \
            &Bs[buf][(w * 32 + c * 8) * 64]);                 \
    }                                                         \
  } while (0)

  const f32x4 fzero = {0.f, 0.f, 0.f, 0.f};
  f32x4 acc[4][4];
#pragma unroll
  for (int i = 0; i < 4; i++)
#pragma unroll
    for (int j = 0; j < 4; j++) acc[i][j] = fzero;

  const int KT = K / BK;
  STAGE(0, gA, gB);  // prologue
  __syncthreads();
  const u16* gAn = gA + BK;
  const u16* gBn = gB + BK;

  for (int T = 0; T < KT; T++) {
    const int cur = T & 1;
    if (T + 1 < KT) {
      STAGE(cur ^ 1, gAn, gBn);
      gAn += BK;
      gBn += BK;
    }
    __builtin_amdgcn_sched_barrier(0);

    bf16x8 a[4][2], bfr[4][2];
#pragma unroll
    for (int i = 0; i < 4; i++)
#pragma unroll
      for (int ks = 0; ks < 2; ks++) {
        int row = wm + i * 16 + lr;
        a[i][ks] = *(const bf16x8*)
            &As[cur][row * 64 + (((ks * 4 + lq) ^ (lr & 7)) * 8)];
      }
#pragma unroll
    for (int j = 0; j < 4; j++)
#pragma unroll
      for (int ks = 0; ks < 2; ks++) {
        int row = wn + j * 16 + lr;
        bfr[j][ks] = *(const bf16x8*)
            &Bs[cur][row * 64 + (((ks * 4 + lq) ^ (lr & 7)) * 8)];
      }
    __builtin_amdgcn_s_setprio(1);
#pragma unroll
    for (int ks = 0; ks < 2; ks++)
#pragma unroll
      for (int i = 0; i < 4; i++)
#pragma unroll
        for (int j = 0; j < 4; j++)
          acc[i][j] = MFMA_G(a[i][ks], bfr[j][ks], acc[i][j]);
    __builtin_amdgcn_s_setprio(0);
    __syncthreads();
  }
#undef STAGE

#pragma unroll
  for (int j = 0; j < 4; j++) {
    int col = n0 + wn + j * 16 + lr;
    float bv = bias[col];
#pragma unroll
    for (int i = 0; i < 4; i++) {
#pragma unroll
      for (int r = 0; r < 4; r++) {
        int row = m0 + wm + i * 16 + lq * 4 + r;
        float val = acc[i][j][r] + bv;
        if (C32) ((float*)C)[(size_t)row * N + col] = val;
        else     ((u16*)C)[(size_t)row * N + col]   = f2bf(val);
      }
    }
  }
}

// ---------------- Flash attention (causal), paired q-tiles ----------------
// Round-7: VALU diet on softmax (r6 was VALU-bound: VALUBusy 49 vs MfmaUtil
// 27; conflict/barrier halving was a null). Changes confined to softmax:
// (a) exp via native exp2f + single FMA: p = 2^(s*C - mn*C), C=0.125*log2e
//     (was sub+mul+exp per element).
// (b) bf16 pack via v_perm_b32 (bit-identical to the old RTZ shift/and/or
//     pack, 1 op per pair instead of 3).
// (c) l via MFMA-ones: 4 chained mfma_16x16x16(ones, pa[j], lacc) give the
//     full row-sum of the SAME bf16 P fed to PV (consistent num/denom);
//     replaces the 17-add psum chain and the epilogue l-shuffles. Each
//     lane's lacc[0] = complete sum for its q-row; rescale touches [0] only.
// Structure (single barrier/kt, dbuf K+V, swizzles) unchanged from r6.
#define KSTR 72  // 64 + 8 pad elems (rows 16B aligned)
#define MFMA16(a, b, c) __builtin_amdgcn_mfma_f32_16x16x32_bf16(a, b, c, 0, 0, 0)
#define MFMA1616(a, b, c) \
  __builtin_amdgcn_mfma_f32_16x16x16bf16_1k(a, b, c, 0, 0, 0)

#define CE 0.18033688011112042f  // 0.125 * log2(e)

// pack two f32 -> dword of 2 bf16 (rtz): [b.hi16 | a.hi16] in one v_perm
__device__ __forceinline__ int permpack(float a, float b) {
  return __builtin_amdgcn_perm(__float_as_uint(b), __float_as_uint(a),
                               0x07060302u);
}

// softmax on raw scores s[4] (one q-row per lane), state (m_, lacc), output
// bf16 P^T frags pa[4]; o rescaled when needed. lacc accumulated by caller.
__device__ __forceinline__ void softmax_pack(f32x4 (&s)[4], s16x4 (&pa)[4],
                                             f32x4 (&o)[4], float& m_,
                                             f32x4& lacc) {
  // in-lane max over 16 (max3-friendly triples), then across lq-group
  float a0 = fmaxf(fmaxf(s[0][0], s[0][1]), s[0][2]);
  float a1 = fmaxf(fmaxf(s[0][3], s[1][0]), s[1][1]);
  float a2 = fmaxf(fmaxf(s[1][2], s[1][3]), s[2][0]);
  float a3 = fmaxf(fmaxf(s[2][1], s[2][2]), s[2][3]);
  float a4 = fmaxf(fmaxf(s[3][0], s[3][1]), s[3][2]);
  float mt = fmaxf(fmaxf(fmaxf(a0, a1), fmaxf(a2, a3)), fmaxf(a4, s[3][3]));
  mt = fmaxf(mt, __shfl_xor(mt, 16));
  mt = fmaxf(mt, __shfl_xor(mt, 32));
  // T13 defer-max: skip rescale while growth small (p bounded by 2^11.5)
  bool need = !__all(mt <= m_ + 64.0f);
  float mn = need ? fmaxf(m_, mt) : m_;
  float mnC = mn * CE;
  if (need) {
    float alpha = exp2f(m_ * CE - mnC);
    m_ = mn;
    lacc[0] *= alpha;  // only [0] is ever read
#pragma unroll
    for (int jd = 0; jd < 4; jd++)
#pragma unroll
      for (int r = 0; r < 4; r++) o[jd][r] *= alpha;
  }
#pragma unroll
  for (int j = 0; j < 4; j++) {
    float p0 = exp2f(__builtin_fmaf(s[j][0], CE, -mnC));
    float p1 = exp2f(__builtin_fmaf(s[j][1], CE, -mnC));
    float p2 = exp2f(__builtin_fmaf(s[j][2], CE, -mnC));
    float p3 = exp2f(__builtin_fmaf(s[j][3], CE, -mnC));
    union { int i[2]; s16x4 v; } pu;
    pu.i[0] = permpack(p0, p1);
    pu.i[1] = permpack(p2, p3);
    pa[j] = pu.v;
  }
}

__device__ __forceinline__ void attn_step(const bf16x8& q0, const bf16x8& q1,
                                          const u16* __restrict__ Kb,
                                          const u16* __restrict__ Vb,
                                          bool diag, int qloc, int lq, int lr,
                                          f32x4 (&o)[4], float& m_,
                                          f32x4& lacc) {
  const f32x4 fzero = {0.f, 0.f, 0.f, 0.f};
  const int swz = (lq ^ ((lr >> 1) & 3)) * 8;
  f32x4 s[4];
  __builtin_amdgcn_s_setprio(1);
#pragma unroll
  for (int j = 0; j < 4; j++) {
    int kr = j * 16 + lr;
    bf16x8 kf0 = *(const bf16x8*)&Kb[kr * 32 + swz];
    bf16x8 kf1 = *(const bf16x8*)&Kb[2048 + kr * 32 + swz];
    f32x4 z = MFMA16(kf0, q0, fzero);  // A=K, B=Q^T -> C = S^T
    s[j] = MFMA16(kf1, q1, z);
  }
  __builtin_amdgcn_s_setprio(0);
  if (diag) {
#pragma unroll
    for (int j = 0; j < 4; j++)
#pragma unroll
      for (int r = 0; r < 4; r++)
        if (16 * j + r > qloc) s[j][r] = -1e30f;
  }
  s16x4 pa[4];
  softmax_pack(s, pa, o, m_, lacc);
  const s16x4 ones = {0x3F80, 0x3F80, 0x3F80, 0x3F80};  // bf16 1.0 x4
  __builtin_amdgcn_s_setprio(1);
#pragma unroll
  for (int jd = 0; jd < 4; jd++) {
    const u16* vrow = &Vb[(jd * 16 + lr) * KSTR + lq * 16];
    union { int4 q; s16x4 h[2]; } va, vb;
    va.q = *(const int4*)vrow;
    vb.q = *(const int4*)(vrow + 8);
    o[jd] = MFMA1616(va.h[0], pa[0], o[jd]);
    o[jd] = MFMA1616(va.h[1], pa[1], o[jd]);
    o[jd] = MFMA1616(vb.h[0], pa[2], o[jd]);
    o[jd] = MFMA1616(vb.h[1], pa[3], o[jd]);
  }
  // l row-sum on the MFMA pipe: C[r][q] = sum_k 1 * P^T[k][q]; every lane's
  // lacc[0] ends with the FULL 64-key sum for its q-row (K summed in-MFMA).
  lacc = MFMA1616(ones, pa[0], lacc);
  lacc = MFMA1616(ones, pa[1], lacc);
  lacc = MFMA1616(ones, pa[2], lacc);
  lacc = MFMA1616(ones, pa[3], lacc);
  __builtin_amdgcn_s_setprio(0);
}

__global__ __launch_bounds__(256, 4) void attn_paired(u16* __restrict__ qkv) {
  __shared__ u16 Ks[2][4096];       // [key*32 + swz d-blk], d-half at +2048
  __shared__ u16 Vs[2][64 * KSTR];  // V^T [d][k'], double-buffered

  const int tid = threadIdx.x;
  const int w = tid >> 6, lane = tid & 63;
  const int lq = lane >> 4, lr = lane & 15;
  const int bh = blockIdx.x, p = blockIdx.y;
  const int h = bh & (NH - 1), b = bh >> 4;
  const int qt0 = p, qt1 = (SL / 64 - 1) - p;
  const int qloc = w * 16 + lr - 4 * lq;

  u16* base = qkv + (size_t)b * SL * N3;
  const u16* kbase = base + NE + h * HD;  // K plane; V plane at +NE

  // K staging: wave w stages chunks {2w,2w+1}; chunk = half*4 + kgrp.
  // Source d-block pre-swizzled by (key>>1)&3 (conflict-free quads).
  const int kg_key = lane >> 2;                         // key within 16-group
  const int kg_blk = (lane & 3) ^ ((kg_key >> 1) & 3);  // source d-block
  const int skey = tid & 63, sd0 = (tid >> 6) * 8;
  const int skeyP = ((skey >> 2) & 3) * 16 + (skey >> 4) * 4 + (skey & 3);
  const u16* vrow0 = base + (size_t)skey * N3 + 2 * NE + h * HD + sd0;

#define KPRE(buf, key0)                                                     \
  {                                                                         \
    _Pragma("unroll") for (int t = 0; t < 2; t++) {                         \
      int chunk = w * 2 + t, half = chunk >> 2, kgrp = chunk & 3;           \
      const u16* g = kbase + (size_t)((key0) + kgrp * 16 + kg_key) * N3 +   \
                     half * 32 + kg_blk * 8;                                \
      gld16(g, &Ks[buf][half * 2048 + kgrp * 512]);                         \
    }                                                                       \
  }
#define VWRITE(buf)                                           \
  {                                                           \
    union { int4 v; u16 u[8]; } t0, t1;                       \
    t0.v = v0; t1.v = v1;                                     \
    u16* Vn = &Vs[buf][0];                                    \
    _Pragma("unroll") for (int j = 0; j < 8; j++) {           \
      Vn[(sd0 + j) * KSTR + skeyP] = t0.u[j];                 \
      Vn[(sd0 + 32 + j) * KSTR + skeyP] = t1.u[j];            \
    }                                                         \
  }

  bf16x8 qf[2][2];
#pragma unroll
  for (int half = 0; half < 2; half++) {
    int qt = half ? qt1 : qt0;
    const u16* qrow = base + (size_t)(qt * 64 + w * 16 + lr) * N3 + h * HD;
    qf[half][0] = *(const bf16x8*)(qrow + lq * 8);
    qf[half][1] = *(const bf16x8*)(qrow + 32 + lq * 8);
  }

  const f32x4 fzero = {0.f, 0.f, 0.f, 0.f};
  f32x4 o[2][4];
  f32x4 lacc[2];
  float m_[2];
#pragma unroll
  for (int half = 0; half < 2; half++) {
    m_[half] = -1e30f;
    lacc[half] = fzero;
#pragma unroll
    for (int jd = 0; jd < 4; jd++) o[half][jd] = fzero;
  }

  // prologue: K(0) DMA; V(0) -> regs -> Vs[0]; V(1) -> regs
  KPRE(0, 0);
  int4 v0 = *(const int4*)vrow0;
  int4 v1 = *(const int4*)(vrow0 + 32);
  asm volatile("s_waitcnt vmcnt(0)" ::: "memory");
  VWRITE(0);
  {
    const u16* nv = vrow0 + (size_t)64 * N3;
    v0 = *(const int4*)nv;
    v1 = *(const int4*)(nv + 32);
  }

  const int ktend = qt1 + 1;  // >= 17 always
  for (int kt = 0; kt < ktend; kt++) {
    // publishes: Ks[kt&1] DMA, Vs[kt&1] writes, v-reg loads (vmcnt+lgkm+bar)
    __syncthreads();
    const int nb = (kt + 1) & 1;
    if (kt + 1 < ktend) {  // stage kt+1 into other buffers; hidden by compute
      KPRE(nb, (kt + 1) * 64);
      VWRITE(nb);
      if (kt + 2 < ktend) {
        const u16* nv = vrow0 + (size_t)(kt + 2) * 64 * N3;
        v0 = *(const int4*)nv;
        v1 = *(const int4*)(nv + 32);
      }
    }
    __builtin_amdgcn_sched_barrier(0);  // pin staging issue before compute

    const u16* Kb = &Ks[kt & 1][0];
    const u16* Vb = &Vs[kt & 1][0];
    attn_step(qf[1][0], qf[1][1], Kb, Vb, kt == qt1, qloc, lq, lr, o[1], m_[1],
              lacc[1]);
    if (kt <= qt0)
      attn_step(qf[0][0], qf[0][1], Kb, Vb, kt == qt0, qloc, lq, lr, o[0],
                m_[0], lacc[0]);
  }

  // epilogue: lacc[half][0] already holds the full l for this lane's q-row
#pragma unroll
  for (int half = 0; half < 2; half++) {
    int qt = half ? qt1 : qt0;
    float inv = 1.0f / lacc[half][0];
    u16* yrow = base + (size_t)(qt * 64 + w * 16 + lr) * N3 + h * HD;
#pragma unroll
    for (int jd = 0; jd < 4; jd++) {
      int2 val;
      val.x = (int)(((unsigned)f2bf(o[half][jd][1] * inv) << 16) |
                    f2bf(o[half][jd][0] * inv));
      val.y = (int)(((unsigned)f2bf(o[half][jd][3] * inv) << 16) |
                    f2bf(o[half][jd][2] * inv));
      *(int2*)(yrow + 16 * jd + 4 * lq) = val;
    }
  }
}

// ---------------- host launch ----------------
extern "C" void kernel_launch(void* const* d_in, const int* in_sizes, int n_in,
                              void* d_out, int out_size, void* d_ws,
                              size_t ws_size, hipStream_t stream) {
  const float* x    = (const float*)d_in[0];
  const float* Wqkv = (const float*)d_in[2];
  const float* bqkv = (const float*)d_in[3];
  const float* Wo   = (const float*)d_in[4];
  const float* bo   = (const float*)d_in[5];

  u16* WqkvT  = (u16*)d_ws;                       // [3072,1024] bf16
  u16* WoT    = WqkvT + (size_t)N3 * NE;          // [1024,1024] bf16
  u16* xb     = WoT + (size_t)NE * NE;            // [8192,1024] bf16
  u16* qkvbuf = xb + (size_t)BS * SL * NE;        // [8192,3072] bf16

  convert_x<<<(BS * SL * NE) / (256 * 8), 256, 0, stream>>>(x, xb);
  transpose_w<<<dim3(N3 / 32, NE / 32), dim3(32, 8), 0, stream>>>(Wqkv, WqkvT,
                                                                  NE, N3);
  transpose_w<<<dim3(NE / 32, NE / 32), dim3(32, 8), 0, stream>>>(Wo, WoT, NE,
                                                                  NE);
  gemm2b<0><<<dim3(N3 / 128, (BS * SL) / 128), 256, 0, stream>>>(
      xb, WqkvT, bqkv, qkvbuf, BS * SL, N3, NE, NE);
  attn_paired<<<dim3(BS * NH, SL / 128), 256, 0, stream>>>(qkvbuf);
  gemm2b<1><<<dim3(NE / 128, (BS * SL) / 128), 256, 0, stream>>>(
      qkvbuf, WoT, bo, d_out, BS * SL, NE, NE, N3);
}

// Round 8
// 261.754 us; speedup vs baseline: 1.0242x; 1.0242x over previous
//
#include <hip/hip_runtime.h>

#define BS 4
#define SL 2048
#define NE 1024
#define NH 16
#define HD 64
#define N3 3072

typedef __attribute__((ext_vector_type(8))) __bf16 bf16x8;
typedef __attribute__((ext_vector_type(4))) float f32x4;
typedef __attribute__((ext_vector_type(4))) short s16x4;
typedef unsigned short u16;

#define CE 0.18033688011112042f  // 0.125 * log2(e): Q pre-scale factor

// raw v_exp_f32 (2^x); exp2f() libcall has precision-guard fixups (r7 lesson)
#if __has_builtin(__builtin_amdgcn_exp2f)
#define EXP2(x) __builtin_amdgcn_exp2f(x)
#else
#define EXP2(x) exp2f(x)
#endif

__device__ __forceinline__ u16 f2bf(float f) {
  union { float f; unsigned int u; } v; v.f = f;
  unsigned int r = v.u + 0x7FFFu + ((v.u >> 16) & 1u);
  return (u16)(r >> 16);
}

// pack two f32 -> dword of 2 bf16 (rtz): [b.hi16 | a.hi16] in one v_perm
// (verified bit-identical in r7: absmax unchanged)
__device__ __forceinline__ int permpack(float a, float b) {
  return __builtin_amdgcn_perm(__float_as_uint(b), __float_as_uint(a),
                               0x07060302u);
}

// global -> LDS direct 16B copy. LDS dest is WAVE-UNIFORM base; HW adds
// lane*16. Global address is per-lane.
__device__ __forceinline__ void gld16(const void* g, void* l) {
#if __has_builtin(__builtin_amdgcn_global_load_lds)
  __builtin_amdgcn_global_load_lds(
      (const __attribute__((address_space(1))) unsigned int*)g,
      (__attribute__((address_space(3))) unsigned int*)l, 16, 0, 0);
#else
  *(int4*)((char*)l + (size_t)(threadIdx.x & 63) * 16) = *(const int4*)g;
#endif
}

// ---------------- x fp32 -> bf16 ----------------
__global__ void convert_x(const float* __restrict__ x, u16* __restrict__ xb) {
  int i = (blockIdx.x * 256 + threadIdx.x) * 8;
  float4 f0 = *(const float4*)(x + i);
  float4 f1 = *(const float4*)(x + i + 4);
  union { int4 v; u16 h[8]; } p;
  p.h[0] = f2bf(f0.x); p.h[1] = f2bf(f0.y);
  p.h[2] = f2bf(f0.z); p.h[3] = f2bf(f0.w);
  p.h[4] = f2bf(f1.x); p.h[5] = f2bf(f1.y);
  p.h[6] = f2bf(f1.z); p.h[7] = f2bf(f1.w);
  *(int4*)(xb + i) = p.v;
}

// ---------------- W transpose+convert: Wt[n*K+k] = bf16(W[k*N+n]) ----------
__global__ void transpose_w(const float* __restrict__ W, u16* __restrict__ Wt,
                            int K, int N) {
  __shared__ u16 tile[32][33];
  int bn = blockIdx.x * 32, bk = blockIdx.y * 32;
  int tx = threadIdx.x, ty = threadIdx.y;  // blockDim = (32, 8)
  for (int r = 0; r < 32; r += 8)
    tile[ty + r][tx] = f2bf(W[(size_t)(bk + ty + r) * N + bn + tx]);
  __syncthreads();
  for (int r = 0; r < 32; r += 8)
    Wt[(size_t)(bn + ty + r) * K + bk + tx] = tile[tx][ty + r];
}

// ============ loose 2-block/CU GEMM (r4 structure; +SCALEQ epilogue) ========
// SCALEQ: multiply output cols [0,NE) (the Q plane) by CE so QK^T emerges
// pre-scaled into the exp2 domain (kills 2 VALU ops per exp in attention).
#define MFMA_G(a, b, c) \
  __builtin_amdgcn_mfma_f32_16x16x32_bf16(a, b, c, 0, 0, 0)

template <int C32, int SCALEQ>
__global__ __launch_bounds__(256, 2) void gemm2b(
    const u16* __restrict__ A, const u16* __restrict__ Bt,
    const float* __restrict__ bias, void* __restrict__ C, int M, int N, int K,
    int lda) {
  constexpr int BM = 128, BN = 128, BK = 64;
  __shared__ u16 As[2][BM * BK];  // 16 KB each
  __shared__ u16 Bs[2][BN * BK];

  const int tid = threadIdx.x;
  const int w = tid >> 6, lane = tid & 63;
  const int lq = lane >> 4, lr = lane & 15;
  const int nwx = gridDim.x;
  const int nwg = nwx * gridDim.y;
  const int lin = blockIdx.y * nwx + blockIdx.x;
  const int cpx = nwg >> 3;
  const int swb = (lin & 7) * cpx + (lin >> 3);
  const int m0 = (swb / nwx) * BM, n0 = (swb % nwx) * BN;
  const int wm = (w >> 1) * 64, wn = (w & 1) * 64;

  const int l8 = lane >> 3, lb = lane & 7;
  const int sw8 = (lb ^ l8) * 8;  // elems
  const u16* gA = A + (size_t)(m0 + w * 32 + l8) * lda + sw8;
  const u16* gB = Bt + (size_t)(n0 + w * 32 + l8) * K + sw8;

#define STAGE(buf, gpa, gpb)                                  \
  do {                                                        \
    _Pragma("unroll") for (int c = 0; c < 4; c++) {           \
      gld16((gpa) + (size_t)(c * 8) * lda,                    \
            &As[buf][(w * 32 + c * 8) * 64]);                 \
      gld16((gpb) + (size_t)(c * 8) * K,                      \
            &Bs[buf][(w * 32 + c * 8) * 64]);                 \
    }                                                         \
  } while (0)

  const f32x4 fzero = {0.f, 0.f, 0.f, 0.f};
  f32x4 acc[4][4];
#pragma unroll
  for (int i = 0; i < 4; i++)
#pragma unroll
    for (int j = 0; j < 4; j++) acc[i][j] = fzero;

  const int KT = K / BK;
  STAGE(0, gA, gB);  // prologue
  __syncthreads();
  const u16* gAn = gA + BK;
  const u16* gBn = gB + BK;

  for (int T = 0; T < KT; T++) {
    const int cur = T & 1;
    if (T + 1 < KT) {
      STAGE(cur ^ 1, gAn, gBn);
      gAn += BK;
      gBn += BK;
    }
    __builtin_amdgcn_sched_barrier(0);

    bf16x8 a[4][2], bfr[4][2];
#pragma unroll
    for (int i = 0; i < 4; i++)
#pragma unroll
      for (int ks = 0; ks < 2; ks++) {
        int row = wm + i * 16 + lr;
        a[i][ks] = *(const bf16x8*)
            &As[cur][row * 64 + (((ks * 4 + lq) ^ (lr & 7)) * 8)];
      }
#pragma unroll
    for (int j = 0; j < 4; j++)
#pragma unroll
      for (int ks = 0; ks < 2; ks++) {
        int row = wn + j * 16 + lr;
        bfr[j][ks] = *(const bf16x8*)
            &Bs[cur][row * 64 + (((ks * 4 + lq) ^ (lr & 7)) * 8)];
      }
    __builtin_amdgcn_s_setprio(1);
#pragma unroll
    for (int ks = 0; ks < 2; ks++)
#pragma unroll
      for (int i = 0; i < 4; i++)
#pragma unroll
        for (int j = 0; j < 4; j++)
          acc[i][j] = MFMA_G(a[i][ks], bfr[j][ks], acc[i][j]);
    __builtin_amdgcn_s_setprio(0);
    __syncthreads();
  }
#undef STAGE

#pragma unroll
  for (int j = 0; j < 4; j++) {
    int col = n0 + wn + j * 16 + lr;
    float bv = bias[col];
    float qs = (SCALEQ && col < NE) ? CE : 1.0f;
#pragma unroll
    for (int i = 0; i < 4; i++) {
#pragma unroll
      for (int r = 0; r < 4; r++) {
        int row = m0 + wm + i * 16 + lq * 4 + r;
        float val = acc[i][j][r] + bv;
        if (SCALEQ) val *= qs;
        if (C32) ((float*)C)[(size_t)row * N + col] = val;
        else     ((u16*)C)[(size_t)row * N + col]   = f2bf(val);
      }
    }
  }
}

// ---------------- Flash attention (causal), paired q-tiles ----------------
// Round-8: r6 softmax structure restored (r7's lacc-MFMA chain + exp2f
// libcall both regressed). Q arrives pre-scaled by CE (gemm epilogue), so
// each exp is v_sub + v_exp_f32 (was sub+mul+mul+exp). permpack kept from
// r7 (1-op pack, verified). Defer-max threshold in exp2 domain: 64*CE=11.54.
// Structure (single barrier/kt, dbuf K+V, swizzles) unchanged from r6.
#define KSTR 72  // 64 + 8 pad elems (rows 16B aligned)
#define MFMA16(a, b, c) __builtin_amdgcn_mfma_f32_16x16x32_bf16(a, b, c, 0, 0, 0)
#define MFMA1616(a, b, c) \
  __builtin_amdgcn_mfma_f32_16x16x16bf16_1k(a, b, c, 0, 0, 0)

// softmax on PRE-SCALED scores s[4] (s = raw*CE; one q-row per lane),
// state (m_, l_); output bf16 P^T frags pa[4]; o rescaled when needed.
__device__ __forceinline__ void softmax_pack(f32x4 (&s)[4], s16x4 (&pa)[4],
                                             f32x4 (&o)[4], float& m_,
                                             float& l_) {
  // in-lane max over 16 (max3-friendly triples), then across lq-group
  float a0 = fmaxf(fmaxf(s[0][0], s[0][1]), s[0][2]);
  float a1 = fmaxf(fmaxf(s[0][3], s[1][0]), s[1][1]);
  float a2 = fmaxf(fmaxf(s[1][2], s[1][3]), s[2][0]);
  float a3 = fmaxf(fmaxf(s[2][1], s[2][2]), s[2][3]);
  float a4 = fmaxf(fmaxf(s[3][0], s[3][1]), s[3][2]);
  float mt = fmaxf(fmaxf(fmaxf(a0, a1), fmaxf(a2, a3)), fmaxf(a4, s[3][3]));
  mt = fmaxf(mt, __shfl_xor(mt, 16));
  mt = fmaxf(mt, __shfl_xor(mt, 32));
  // T13 defer-max: skip rescale while growth small (p bounded by 2^11.54)
  bool need = !__all(mt <= m_ + 11.54f);
  float mn = need ? fmaxf(m_, mt) : m_;
  if (need) {
    float alpha = EXP2(m_ - mn);
    m_ = mn;
    l_ *= alpha;
#pragma unroll
    for (int jd = 0; jd < 4; jd++)
#pragma unroll
      for (int r = 0; r < 4; r++) o[jd][r] *= alpha;
  }
  float psum = 0.f;
#pragma unroll
  for (int j = 0; j < 4; j++) {
    float p0 = EXP2(s[j][0] - mn);
    float p1 = EXP2(s[j][1] - mn);
    float p2 = EXP2(s[j][2] - mn);
    float p3 = EXP2(s[j][3] - mn);
    psum += (p0 + p1) + (p2 + p3);
    union { int i[2]; s16x4 v; } pu;
    pu.i[0] = permpack(p0, p1);
    pu.i[1] = permpack(p2, p3);
    pa[j] = pu.v;
  }
  l_ += psum;  // per-lane partial (this lane's k-quarter)
}

__device__ __forceinline__ void attn_step(const bf16x8& q0, const bf16x8& q1,
                                          const u16* __restrict__ Kb,
                                          const u16* __restrict__ Vb,
                                          bool diag, int qloc, int lq, int lr,
                                          f32x4 (&o)[4], float& m_, float& l_) {
  const f32x4 fzero = {0.f, 0.f, 0.f, 0.f};
  const int swz = (lq ^ ((lr >> 1) & 3)) * 8;
  f32x4 s[4];
  __builtin_amdgcn_s_setprio(1);
#pragma unroll
  for (int j = 0; j < 4; j++) {
    int kr = j * 16 + lr;
    bf16x8 kf0 = *(const bf16x8*)&Kb[kr * 32 + swz];
    bf16x8 kf1 = *(const bf16x8*)&Kb[2048 + kr * 32 + swz];
    f32x4 z = MFMA16(kf0, q0, fzero);  // A=K, B=Q^T -> C = S^T (pre-scaled)
    s[j] = MFMA16(kf1, q1, z);
  }
  __builtin_amdgcn_s_setprio(0);
  if (diag) {
#pragma unroll
    for (int j = 0; j < 4; j++)
#pragma unroll
      for (int r = 0; r < 4; r++)
        if (16 * j + r > qloc) s[j][r] = -1e30f;
  }
  s16x4 pa[4];
  softmax_pack(s, pa, o, m_, l_);
  __builtin_amdgcn_s_setprio(1);
#pragma unroll
  for (int jd = 0; jd < 4; jd++) {
    const u16* vrow = &Vb[(jd * 16 + lr) * KSTR + lq * 16];
    union { int4 q; s16x4 h[2]; } va, vb;
    va.q = *(const int4*)vrow;
    vb.q = *(const int4*)(vrow + 8);
    o[jd] = MFMA1616(va.h[0], pa[0], o[jd]);
    o[jd] = MFMA1616(va.h[1], pa[1], o[jd]);
    o[jd] = MFMA1616(vb.h[0], pa[2], o[jd]);
    o[jd] = MFMA1616(vb.h[1], pa[3], o[jd]);
  }
  __builtin_amdgcn_s_setprio(0);
}

__global__ __launch_bounds__(256, 4) void attn_paired(u16* __restrict__ qkv) {
  __shared__ u16 Ks[2][4096];       // [key*32 + swz d-blk], d-half at +2048
  __shared__ u16 Vs[2][64 * KSTR];  // V^T [d][k'], double-buffered

  const int tid = threadIdx.x;
  const int w = tid >> 6, lane = tid & 63;
  const int lq = lane >> 4, lr = lane & 15;
  const int bh = blockIdx.x, p = blockIdx.y;
  const int h = bh & (NH - 1), b = bh >> 4;
  const int qt0 = p, qt1 = (SL / 64 - 1) - p;
  const int qloc = w * 16 + lr - 4 * lq;

  u16* base = qkv + (size_t)b * SL * N3;
  const u16* kbase = base + NE + h * HD;  // K plane; V plane at +NE

  // K staging: wave w stages chunks {2w,2w+1}; chunk = half*4 + kgrp.
  // Source d-block pre-swizzled by (key>>1)&3 (conflict-free quads).
  const int kg_key = lane >> 2;                         // key within 16-group
  const int kg_blk = (lane & 3) ^ ((kg_key >> 1) & 3);  // source d-block
  const int skey = tid & 63, sd0 = (tid >> 6) * 8;
  const int skeyP = ((skey >> 2) & 3) * 16 + (skey >> 4) * 4 + (skey & 3);
  const u16* vrow0 = base + (size_t)skey * N3 + 2 * NE + h * HD + sd0;

#define KPRE(buf, key0)                                                     \
  {                                                                         \
    _Pragma("unroll") for (int t = 0; t < 2; t++) {                         \
      int chunk = w * 2 + t, half = chunk >> 2, kgrp = chunk & 3;           \
      const u16* g = kbase + (size_t)((key0) + kgrp * 16 + kg_key) * N3 +   \
                     half * 32 + kg_blk * 8;                                \
      gld16(g, &Ks[buf][half * 2048 + kgrp * 512]);                         \
    }                                                                       \
  }
#define VWRITE(buf)                                           \
  {                                                           \
    union { int4 v; u16 u[8]; } t0, t1;                       \
    t0.v = v0; t1.v = v1;                                     \
    u16* Vn = &Vs[buf][0];                                    \
    _Pragma("unroll") for (int j = 0; j < 8; j++) {           \
      Vn[(sd0 + j) * KSTR + skeyP] = t0.u[j];                 \
      Vn[(sd0 + 32 + j) * KSTR + skeyP] = t1.u[j];            \
    }                                                         \
  }

  bf16x8 qf[2][2];
#pragma unroll
  for (int half = 0; half < 2; half++) {
    int qt = half ? qt1 : qt0;
    const u16* qrow = base + (size_t)(qt * 64 + w * 16 + lr) * N3 + h * HD;
    qf[half][0] = *(const bf16x8*)(qrow + lq * 8);
    qf[half][1] = *(const bf16x8*)(qrow + 32 + lq * 8);
  }

  const f32x4 fzero = {0.f, 0.f, 0.f, 0.f};
  f32x4 o[2][4];
  float m_[2], l_[2];
#pragma unroll
  for (int half = 0; half < 2; half++) {
    m_[half] = -1e30f;
    l_[half] = 0.f;
#pragma unroll
    for (int jd = 0; jd < 4; jd++) o[half][jd] = fzero;
  }

  // prologue: K(0) DMA; V(0) -> regs -> Vs[0]; V(1) -> regs
  KPRE(0, 0);
  int4 v0 = *(const int4*)vrow0;
  int4 v1 = *(const int4*)(vrow0 + 32);
  asm volatile("s_waitcnt vmcnt(0)" ::: "memory");
  VWRITE(0);
  {
    const u16* nv = vrow0 + (size_t)64 * N3;
    v0 = *(const int4*)nv;
    v1 = *(const int4*)(nv + 32);
  }

  const int ktend = qt1 + 1;  // >= 17 always
  for (int kt = 0; kt < ktend; kt++) {
    // publishes: Ks[kt&1] DMA, Vs[kt&1] writes, v-reg loads (vmcnt+lgkm+bar)
    __syncthreads();
    const int nb = (kt + 1) & 1;
    if (kt + 1 < ktend) {  // stage kt+1 into other buffers; hidden by compute
      KPRE(nb, (kt + 1) * 64);
      VWRITE(nb);
      if (kt + 2 < ktend) {
        const u16* nv = vrow0 + (size_t)(kt + 2) * 64 * N3;
        v0 = *(const int4*)nv;
        v1 = *(const int4*)(nv + 32);
      }
    }
    __builtin_amdgcn_sched_barrier(0);  // pin staging issue before compute

    const u16* Kb = &Ks[kt & 1][0];
    const u16* Vb = &Vs[kt & 1][0];
    attn_step(qf[1][0], qf[1][1], Kb, Vb, kt == qt1, qloc, lq, lr, o[1], m_[1],
              l_[1]);
    if (kt <= qt0)
      attn_step(qf[0][0], qf[0][1], Kb, Vb, kt == qt0, qloc, lq, lr, o[0],
                m_[0], l_[0]);
  }

  // epilogue: reduce per-lane l partials, write Y over the Q slot
#pragma unroll
  for (int half = 0; half < 2; half++) {
    int qt = half ? qt1 : qt0;
    float lsum = l_[half];
    lsum += __shfl_xor(lsum, 16);
    lsum += __shfl_xor(lsum, 32);
    float inv = 1.0f / lsum;
    u16* yrow = base + (size_t)(qt * 64 + w * 16 + lr) * N3 + h * HD;
#pragma unroll
    for (int jd = 0; jd < 4; jd++) {
      int2 val;
      val.x = (int)(((unsigned)f2bf(o[half][jd][1] * inv) << 16) |
                    f2bf(o[half][jd][0] * inv));
      val.y = (int)(((unsigned)f2bf(o[half][jd][3] * inv) << 16) |
                    f2bf(o[half][jd][2] * inv));
      *(int2*)(yrow + 16 * jd + 4 * lq) = val;
    }
  }
}

// ---------------- host launch ----------------
extern "C" void kernel_launch(void* const* d_in, const int* in_sizes, int n_in,
                              void* d_out, int out_size, void* d_ws,
                              size_t ws_size, hipStream_t stream) {
  const float* x    = (const float*)d_in[0];
  const float* Wqkv = (const float*)d_in[2];
  const float* bqkv = (const float*)d_in[3];
  const float* Wo   = (const float*)d_in[4];
  const float* bo   = (const float*)d_in[5];

  u16* WqkvT  = (u16*)d_ws;                       // [3072,1024] bf16
  u16* WoT    = WqkvT + (size_t)N3 * NE;          // [1024,1024] bf16
  u16* xb     = WoT + (size_t)NE * NE;            // [8192,1024] bf16
  u16* qkvbuf = xb + (size_t)BS * SL * NE;        // [8192,3072] bf16

  convert_x<<<(BS * SL * NE) / (256 * 8), 256, 0, stream>>>(x, xb);
  transpose_w<<<dim3(N3 / 32, NE / 32), dim3(32, 8), 0, stream>>>(Wqkv, WqkvT,
                                                                  NE, N3);
  transpose_w<<<dim3(NE / 32, NE / 32), dim3(32, 8), 0, stream>>>(Wo, WoT, NE,
                                                                  NE);
  gemm2b<0, 1><<<dim3(N3 / 128, (BS * SL) / 128), 256, 0, stream>>>(
      xb, WqkvT, bqkv, qkvbuf, BS * SL, N3, NE, NE);
  attn_paired<<<dim3(BS * NH, SL / 128), 256, 0, stream>>>(qkvbuf);
  gemm2b<1, 0><<<dim3(NE / 128, (BS * SL) / 128), 256, 0, stream>>>(
      qkvbuf, WoT, bo, d_out, BS * SL, NE, NE, N3);
}

// Round 9
// 259.755 us; speedup vs baseline: 1.0320x; 1.0077x over previous
//
#include <hip/hip_runtime.h>

#define BS 4
#define SL 2048
#define NE 1024
#define NH 16
#define HD 64
#define N3 3072

typedef __attribute__((ext_vector_type(8))) __bf16 bf16x8;
typedef __attribute__((ext_vector_type(4))) float f32x4;
typedef __attribute__((ext_vector_type(4))) short s16x4;
typedef unsigned short u16;

#define CE 0.18033688011112042f  // 0.125 * log2(e): Q pre-scale factor

// raw v_exp_f32 (2^x); exp2f() libcall has precision-guard fixups (r7 lesson)
#if __has_builtin(__builtin_amdgcn_exp2f)
#define EXP2(x) __builtin_amdgcn_exp2f(x)
#else
#define EXP2(x) exp2f(x)
#endif

__device__ __forceinline__ u16 f2bf(float f) {
  union { float f; unsigned int u; } v; v.f = f;
  unsigned int r = v.u + 0x7FFFu + ((v.u >> 16) & 1u);
  return (u16)(r >> 16);
}

// pack two f32 -> dword of 2 bf16 (rtz): [b.hi16 | a.hi16] in one v_perm
__device__ __forceinline__ int permpack(float a, float b) {
  return __builtin_amdgcn_perm(__float_as_uint(b), __float_as_uint(a),
                               0x07060302u);
}

// global -> LDS direct 16B copy. LDS dest is WAVE-UNIFORM base; HW adds
// lane*16. Global address is per-lane.
__device__ __forceinline__ void gld16(const void* g, void* l) {
#if __has_builtin(__builtin_amdgcn_global_load_lds)
  __builtin_amdgcn_global_load_lds(
      (const __attribute__((address_space(1))) unsigned int*)g,
      (__attribute__((address_space(3))) unsigned int*)l, 16, 0, 0);
#else
  *(int4*)((char*)l + (size_t)(threadIdx.x & 63) * 16) = *(const int4*)g;
#endif
}

// counted vmcnt wait (compile-time literal)
template <int N>
__device__ __forceinline__ void vmw() {
  if constexpr (N == 0)
    asm volatile("s_waitcnt vmcnt(0)" ::: "memory");
  else if constexpr (N == 4)
    asm volatile("s_waitcnt vmcnt(4)" ::: "memory");
}

// ---------------- x fp32 -> bf16 ----------------
__global__ void convert_x(const float* __restrict__ x, u16* __restrict__ xb) {
  int i = (blockIdx.x * 256 + threadIdx.x) * 8;
  float4 f0 = *(const float4*)(x + i);
  float4 f1 = *(const float4*)(x + i + 4);
  union { int4 v; u16 h[8]; } p;
  p.h[0] = f2bf(f0.x); p.h[1] = f2bf(f0.y);
  p.h[2] = f2bf(f0.z); p.h[3] = f2bf(f0.w);
  p.h[4] = f2bf(f1.x); p.h[5] = f2bf(f1.y);
  p.h[6] = f2bf(f1.z); p.h[7] = f2bf(f1.w);
  *(int4*)(xb + i) = p.v;
}

// ---------------- W transpose+convert: Wt[n*K+k] = bf16(W[k*N+n]) ----------
__global__ void transpose_w(const float* __restrict__ W, u16* __restrict__ Wt,
                            int K, int N) {
  __shared__ u16 tile[32][33];
  int bn = blockIdx.x * 32, bk = blockIdx.y * 32;
  int tx = threadIdx.x, ty = threadIdx.y;  // blockDim = (32, 8)
  for (int r = 0; r < 32; r += 8)
    tile[ty + r][tx] = f2bf(W[(size_t)(bk + ty + r) * N + bn + tx]);
  __syncthreads();
  for (int r = 0; r < 32; r += 8)
    Wt[(size_t)(bn + ty + r) * K + bk + tx] = tile[tx][ty + r];
}

// ======== 3-buffer depth-2 GEMM (BK=32, 3 blocks/CU, counted vmcnt) ========
// C[M,N] = A[M,K] @ Bt[N,K]^T + bias[N].  BM=BN=128, BK=32, 4 waves (2x2).
// r8's gemm2b waited vmcnt(0)-in-syncthreads on loads issued ONE tile body
// (~500 cy) earlier — under HBM latency (the same depth bug that sank the
// 8-phase ports at 24% MfmaUtil). Fix: 3 buffers x 16 KB (48 KB -> 3
// blocks/CU) with DEPTH-2 prefetch: iter T stages tile T+2, ends with
// vmcnt(4) (drains tile T+1's 4 loads, leaves T+2 in flight — never 0
// mid-loop) + raw s_barrier. Wait distance = 2 tile bodies >= HBM latency.
// WAR safety: buf[stg]=tile T-1's reads completed before the end-of-(T-1)
// barrier (per-wave lgkm drained before its MFMA), DMA issues after it.
// LDS swizzle for 64 B rows: s(row) = (row>>1)&3, both-sides (source
// col-block pre-swizzle + swizzled ds_read addr); 2-way aliasing only.
#define MFMA_G(a, b, c) \
  __builtin_amdgcn_mfma_f32_16x16x32_bf16(a, b, c, 0, 0, 0)
#define GBAR()                         \
  do {                                 \
    __builtin_amdgcn_s_barrier();      \
    __builtin_amdgcn_sched_barrier(0); \
  } while (0)

template <int C32, int SCALEQ>
__global__ __launch_bounds__(256, 3) void gemm3b(
    const u16* __restrict__ A, const u16* __restrict__ Bt,
    const float* __restrict__ bias, void* __restrict__ C, int M, int N, int K,
    int lda) {
  constexpr int BM = 128, BN = 128, BK = 32;
  constexpr int TSZ = BM * BK;     // 4096 elems = 8 KB
  __shared__ u16 As[3][TSZ];
  __shared__ u16 Bs[3][TSZ];

  const int tid = threadIdx.x;
  const int w = tid >> 6, lane = tid & 63;
  const int lq = lane >> 4, lr = lane & 15;
  const int nwx = gridDim.x;
  const int nwg = nwx * gridDim.y;
  const int lin = blockIdx.y * nwx + blockIdx.x;
  const int cpx = nwg >> 3;
  const int swb = (lin & 7) * cpx + (lin >> 3);
  const int m0 = (swb / nwx) * BM, n0 = (swb % nwx) * BN;
  const int wm = (w >> 1) * 64, wn = (w & 1) * 64;

  // staging source: 1 gld16 = 16 rows x 64 B; lane -> row=lane>>2,
  // blk=lane&3; source col-block = blk ^ ((row>>1)&3)
  const int srow = lane >> 2;
  const int swcol = ((lane & 3) ^ ((lane >> 3) & 3)) * 8;  // elems
  const u16* gA = A + (size_t)(m0 + w * 32 + srow) * lda + swcol;
  const u16* gB = Bt + (size_t)(n0 + w * 32 + srow) * K + swcol;

#define STAGE3(abuf, bbuf, gpa, gpb)                          \
  do {                                                        \
    _Pragma("unroll") for (int c = 0; c < 2; c++) {           \
      gld16((gpa) + (size_t)(c * 16) * lda,                   \
            (abuf) + (w * 32 + c * 16) * 32);                 \
      gld16((gpb) + (size_t)(c * 16) * K,                     \
            (bbuf) + (w * 32 + c * 16) * 32);                 \
    }                                                         \
  } while (0)

  const f32x4 fzero = {0.f, 0.f, 0.f, 0.f};
  f32x4 acc[4][4];
#pragma unroll
  for (int i = 0; i < 4; i++)
#pragma unroll
    for (int j = 0; j < 4; j++) acc[i][j] = fzero;

  const int KT = K / BK;
  u16* asb = &As[0][0];
  u16* bsb = &Bs[0][0];
  // prologue: tiles 0,1 -> bufs 0,1; drain tile 0 (vmcnt(4)), publish.
  STAGE3(asb, bsb, gA, gB);
  STAGE3(asb + TSZ, bsb + TSZ, gA + BK, gB + BK);
  vmw<4>();
  GBAR();
  const u16* gAn = gA + 2 * BK;
  const u16* gBn = gB + 2 * BK;

  int cur = 0, stg = 2;
  const int fswz = (lq ^ ((lr >> 1) & 3)) * 8;  // fragment swizzle (elems)
  for (int T = 0; T < KT; T++) {
    if (T + 2 < KT) {  // stage tile T+2 into buf[stg] (holds tile T-1)
      STAGE3(asb + stg * TSZ, bsb + stg * TSZ, gAn, gBn);
      gAn += BK;
      gBn += BK;
    }
    __builtin_amdgcn_sched_barrier(0);  // pin staging issue first

    const u16* Ac = asb + cur * TSZ;
    const u16* Bc = bsb + cur * TSZ;
    bf16x8 a[4], b[4];
#pragma unroll
    for (int i = 0; i < 4; i++)
      a[i] = *(const bf16x8*)&Ac[(wm + i * 16 + lr) * 32 + fswz];
#pragma unroll
    for (int j = 0; j < 4; j++)
      b[j] = *(const bf16x8*)&Bc[(wn + j * 16 + lr) * 32 + fswz];
    __builtin_amdgcn_s_setprio(1);
#pragma unroll
    for (int i = 0; i < 4; i++)
#pragma unroll
      for (int j = 0; j < 4; j++)
        acc[i][j] = MFMA_G(a[i], b[j], acc[i][j]);
    __builtin_amdgcn_s_setprio(0);

    if (T + 2 < KT) {
      vmw<4>();  // drain tile T+1's 4 loads; tile T+2's stay in flight
      GBAR();
    } else if (T + 1 < KT) {
      vmw<0>();  // tail: drain the last tile
      GBAR();
    }
    cur = (cur == 2) ? 0 : cur + 1;
    stg = (stg == 2) ? 0 : stg + 1;
  }
#undef STAGE3

  // epilogue. C/D layout: col = lane&15, row = (lane>>4)*4 + reg.
#pragma unroll
  for (int j = 0; j < 4; j++) {
    int col = n0 + wn + j * 16 + lr;
    float bv = bias[col];
    float qs = (SCALEQ && col < NE) ? CE : 1.0f;
#pragma unroll
    for (int i = 0; i < 4; i++) {
#pragma unroll
      for (int r = 0; r < 4; r++) {
        int row = m0 + wm + i * 16 + lq * 4 + r;
        float val = acc[i][j][r] + bv;
        if (SCALEQ) val *= qs;
        if (C32) ((float*)C)[(size_t)row * N + col] = val;
        else     ((u16*)C)[(size_t)row * N + col]   = f2bf(val);
      }
    }
  }
}

// ---------------- Flash attention (causal), paired q-tiles ----------------
// Round-9 delta: V staging pairs keys {2a, 2a+1} (adjacent in permuted k'
// by construction) -> 8 ds_write_b32 via 8 v_perm packs, replacing 16
// scalar ds_write_b16 + their address math. Banking: lanes 0-31 hit 32
// distinct banks, lanes 32-63 alias 2-way (free). Rest unchanged from r8
// (Q pre-scaled by CE in gemm epilogue, raw v_exp, permpack, defer-max,
// single barrier/kt, dbuf K+V, K swizzle (key>>1)&3).
#define KSTR 72  // 64 + 8 pad elems (rows 16B aligned)
#define MFMA16(a, b, c) __builtin_amdgcn_mfma_f32_16x16x32_bf16(a, b, c, 0, 0, 0)
#define MFMA1616(a, b, c) \
  __builtin_amdgcn_mfma_f32_16x16x16bf16_1k(a, b, c, 0, 0, 0)

// softmax on PRE-SCALED scores s[4] (s = raw*CE; one q-row per lane),
// state (m_, l_); output bf16 P^T frags pa[4]; o rescaled when needed.
__device__ __forceinline__ void softmax_pack(f32x4 (&s)[4], s16x4 (&pa)[4],
                                             f32x4 (&o)[4], float& m_,
                                             float& l_) {
  // in-lane max over 16 (max3-friendly triples), then across lq-group
  float a0 = fmaxf(fmaxf(s[0][0], s[0][1]), s[0][2]);
  float a1 = fmaxf(fmaxf(s[0][3], s[1][0]), s[1][1]);
  float a2 = fmaxf(fmaxf(s[1][2], s[1][3]), s[2][0]);
  float a3 = fmaxf(fmaxf(s[2][1], s[2][2]), s[2][3]);
  float a4 = fmaxf(fmaxf(s[3][0], s[3][1]), s[3][2]);
  float mt = fmaxf(fmaxf(fmaxf(a0, a1), fmaxf(a2, a3)), fmaxf(a4, s[3][3]));
  mt = fmaxf(mt, __shfl_xor(mt, 16));
  mt = fmaxf(mt, __shfl_xor(mt, 32));
  // T13 defer-max: skip rescale while growth small (p bounded by 2^11.54)
  bool need = !__all(mt <= m_ + 11.54f);
  float mn = need ? fmaxf(m_, mt) : m_;
  if (need) {
    float alpha = EXP2(m_ - mn);
    m_ = mn;
    l_ *= alpha;
#pragma unroll
    for (int jd = 0; jd < 4; jd++)
#pragma unroll
      for (int r = 0; r < 4; r++) o[jd][r] *= alpha;
  }
  float psum = 0.f;
#pragma unroll
  for (int j = 0; j < 4; j++) {
    float p0 = EXP2(s[j][0] - mn);
    float p1 = EXP2(s[j][1] - mn);
    float p2 = EXP2(s[j][2] - mn);
    float p3 = EXP2(s[j][3] - mn);
    psum += (p0 + p1) + (p2 + p3);
    union { int i[2]; s16x4 v; } pu;
    pu.i[0] = permpack(p0, p1);
    pu.i[1] = permpack(p2, p3);
    pa[j] = pu.v;
  }
  l_ += psum;  // per-lane partial (this lane's k-quarter)
}

__device__ __forceinline__ void attn_step(const bf16x8& q0, const bf16x8& q1,
                                          const u16* __restrict__ Kb,
                                          const u16* __restrict__ Vb,
                                          bool diag, int qloc, int lq, int lr,
                                          f32x4 (&o)[4], float& m_, float& l_) {
  const f32x4 fzero = {0.f, 0.f, 0.f, 0.f};
  const int swz = (lq ^ ((lr >> 1) & 3)) * 8;
  f32x4 s[4];
  __builtin_amdgcn_s_setprio(1);
#pragma unroll
  for (int j = 0; j < 4; j++) {
    int kr = j * 16 + lr;
    bf16x8 kf0 = *(const bf16x8*)&Kb[kr * 32 + swz];
    bf16x8 kf1 = *(const bf16x8*)&Kb[2048 + kr * 32 + swz];
    f32x4 z = MFMA16(kf0, q0, fzero);  // A=K, B=Q^T -> C = S^T (pre-scaled)
    s[j] = MFMA16(kf1, q1, z);
  }
  __builtin_amdgcn_s_setprio(0);
  if (diag) {
#pragma unroll
    for (int j = 0; j < 4; j++)
#pragma unroll
      for (int r = 0; r < 4; r++)
        if (16 * j + r > qloc) s[j][r] = -1e30f;
  }
  s16x4 pa[4];
  softmax_pack(s, pa, o, m_, l_);
  __builtin_amdgcn_s_setprio(1);
#pragma unroll
  for (int jd = 0; jd < 4; jd++) {
    const u16* vrow = &Vb[(jd * 16 + lr) * KSTR + lq * 16];
    union { int4 q; s16x4 h[2]; } va, vb;
    va.q = *(const int4*)vrow;
    vb.q = *(const int4*)(vrow + 8);
    o[jd] = MFMA1616(va.h[0], pa[0], o[jd]);
    o[jd] = MFMA1616(va.h[1], pa[1], o[jd]);
    o[jd] = MFMA1616(vb.h[0], pa[2], o[jd]);
    o[jd] = MFMA1616(vb.h[1], pa[3], o[jd]);
  }
  __builtin_amdgcn_s_setprio(0);
}

__global__ __launch_bounds__(256, 4) void attn_paired(u16* __restrict__ qkv) {
  __shared__ u16 Ks[2][4096];       // [key*32 + swz d-blk], d-half at +2048
  __shared__ u16 Vs[2][64 * KSTR];  // V^T [d][k'], double-buffered

  const int tid = threadIdx.x;
  const int w = tid >> 6, lane = tid & 63;
  const int lq = lane >> 4, lr = lane & 15;
  const int bh = blockIdx.x, p = blockIdx.y;
  const int h = bh & (NH - 1), b = bh >> 4;
  const int qt0 = p, qt1 = (SL / 64 - 1) - p;
  const int qloc = w * 16 + lr - 4 * lq;

  u16* base = qkv + (size_t)b * SL * N3;
  const u16* kbase = base + NE + h * HD;  // K plane; V plane at +NE

  // K staging: wave w stages chunks {2w,2w+1}; chunk = half*4 + kgrp.
  // Source d-block pre-swizzled by (key>>1)&3 (conflict-free quads).
  const int kg_key = lane >> 2;                         // key within 16-group
  const int kg_blk = (lane & 3) ^ ((kg_key >> 1) & 3);  // source d-block
  // V staging: thread owns keys {k0, k0+1}, d-rows [sd0, sd0+8)
  const int sd0 = (tid >> 5) * 8;
  const int k0 = (tid & 31) * 2;
  const int k0p = ((k0 >> 2) & 3) * 16 + (k0 >> 4) * 4 + (k0 & 3);
  const u16* vrow0 = base + (size_t)k0 * N3 + 2 * NE + h * HD + sd0;

#define KPRE(buf, key0)                                                     \
  {                                                                         \
    _Pragma("unroll") for (int t = 0; t < 2; t++) {                         \
      int chunk = w * 2 + t, half = chunk >> 2, kgrp = chunk & 3;           \
      const u16* g = kbase + (size_t)((key0) + kgrp * 16 + kg_key) * N3 +   \
                     half * 32 + kg_blk * 8;                                \
      gld16(g, &Ks[buf][half * 2048 + kgrp * 512]);                         \
    }                                                                       \
  }
// paired-key b32 V write: lo = [k1.u16 | k0.u16] of u16 slot 2dw,
// hi = slot 2dw+1 (v_perm sel: bytes 0-3 from src1, 4-7 from src0)
#define VWRITE(buf)                                                        \
  {                                                                        \
    union { int4 v; int d[4]; } t0, t1;                                    \
    t0.v = v0; t1.v = v1;                                                  \
    u16* Vn = &Vs[buf][0];                                                 \
    _Pragma("unroll") for (int dw = 0; dw < 4; dw++) {                     \
      int lo = __builtin_amdgcn_perm((unsigned)t1.d[dw],                   \
                                     (unsigned)t0.d[dw], 0x05040100u);     \
      int hi = __builtin_amdgcn_perm((unsigned)t1.d[dw],                   \
                                     (unsigned)t0.d[dw], 0x07060302u);     \
      *(int*)&Vn[(sd0 + 2 * dw) * KSTR + k0p] = lo;                        \
      *(int*)&Vn[(sd0 + 2 * dw + 1) * KSTR + k0p] = hi;                    \
    }                                                                      \
  }

  bf16x8 qf[2][2];
#pragma unroll
  for (int half = 0; half < 2; half++) {
    int qt = half ? qt1 : qt0;
    const u16* qrow = base + (size_t)(qt * 64 + w * 16 + lr) * N3 + h * HD;
    qf[half][0] = *(const bf16x8*)(qrow + lq * 8);
    qf[half][1] = *(const bf16x8*)(qrow + 32 + lq * 8);
  }

  const f32x4 fzero = {0.f, 0.f, 0.f, 0.f};
  f32x4 o[2][4];
  float m_[2], l_[2];
#pragma unroll
  for (int half = 0; half < 2; half++) {
    m_[half] = -1e30f;
    l_[half] = 0.f;
#pragma unroll
    for (int jd = 0; jd < 4; jd++) o[half][jd] = fzero;
  }

  // prologue: K(0) DMA; V(0) rows k0,k1 -> regs -> Vs[0]; V(1) -> regs
  KPRE(0, 0);
  int4 v0 = *(const int4*)vrow0;
  int4 v1 = *(const int4*)(vrow0 + N3);
  asm volatile("s_waitcnt vmcnt(0)" ::: "memory");
  VWRITE(0);
  {
    const u16* nv = vrow0 + (size_t)64 * N3;
    v0 = *(const int4*)nv;
    v1 = *(const int4*)(nv + N3);
  }

  const int ktend = qt1 + 1;  // >= 17 always
  for (int kt = 0; kt < ktend; kt++) {
    // publishes: Ks[kt&1] DMA, Vs[kt&1] writes, v-reg loads (vmcnt+lgkm+bar)
    __syncthreads();
    const int nb = (kt + 1) & 1;
    if (kt + 1 < ktend) {  // stage kt+1 into other buffers; hidden by compute
      KPRE(nb, (kt + 1) * 64);
      VWRITE(nb);
      if (kt + 2 < ktend) {
        const u16* nv = vrow0 + (size_t)(kt + 2) * 64 * N3;
        v0 = *(const int4*)nv;
        v1 = *(const int4*)(nv + N3);
      }
    }
    __builtin_amdgcn_sched_barrier(0);  // pin staging issue before compute

    const u16* Kb = &Ks[kt & 1][0];
    const u16* Vb = &Vs[kt & 1][0];
    attn_step(qf[1][0], qf[1][1], Kb, Vb, kt == qt1, qloc, lq, lr, o[1], m_[1],
              l_[1]);
    if (kt <= qt0)
      attn_step(qf[0][0], qf[0][1], Kb, Vb, kt == qt0, qloc, lq, lr, o[0],
                m_[0], l_[0]);
  }

  // epilogue: reduce per-lane l partials, write Y over the Q slot
#pragma unroll
  for (int half = 0; half < 2; half++) {
    int qt = half ? qt1 : qt0;
    float lsum = l_[half];
    lsum += __shfl_xor(lsum, 16);
    lsum += __shfl_xor(lsum, 32);
    float inv = 1.0f / lsum;
    u16* yrow = base + (size_t)(qt * 64 + w * 16 + lr) * N3 + h * HD;
#pragma unroll
    for (int jd = 0; jd < 4; jd++) {
      int2 val;
      val.x = (int)(((unsigned)f2bf(o[half][jd][1] * inv) << 16) |
                    f2bf(o[half][jd][0] * inv));
      val.y = (int)(((unsigned)f2bf(o[half][jd][3] * inv) << 16) |
                    f2bf(o[half][jd][2] * inv));
      *(int2*)(yrow + 16 * jd + 4 * lq) = val;
    }
  }
}

// ---------------- host launch ----------------
extern "C" void kernel_launch(void* const* d_in, const int* in_sizes, int n_in,
                              void* d_out, int out_size, void* d_ws,
                              size_t ws_size, hipStream_t stream) {
  const float* x    = (const float*)d_in[0];
  const float* Wqkv = (const float*)d_in[2];
  const float* bqkv = (const float*)d_in[3];
  const float* Wo   = (const float*)d_in[4];
  const float* bo   = (const float*)d_in[5];

  u16* WqkvT  = (u16*)d_ws;                       // [3072,1024] bf16
  u16* WoT    = WqkvT + (size_t)N3 * NE;          // [1024,1024] bf16
  u16* xb     = WoT + (size_t)NE * NE;            // [8192,1024] bf16
  u16* qkvbuf = xb + (size_t)BS * SL * NE;        // [8192,3072] bf16

  convert_x<<<(BS * SL * NE) / (256 * 8), 256, 0, stream>>>(x, xb);
  transpose_w<<<dim3(N3 / 32, NE / 32), dim3(32, 8), 0, stream>>>(Wqkv, WqkvT,
                                                                  NE, N3);
  transpose_w<<<dim3(NE / 32, NE / 32), dim3(32, 8), 0, stream>>>(Wo, WoT, NE,
                                                                  NE);
  gemm3b<0, 1><<<dim3(N3 / 128, (BS * SL) / 128), 256, 0, stream>>>(
      xb, WqkvT, bqkv, qkvbuf, BS * SL, N3, NE, NE);
  attn_paired<<<dim3(BS * NH, SL / 128), 256, 0, stream>>>(qkvbuf);
  gemm3b<1, 0><<<dim3(NE / 128, (BS * SL) / 128), 256, 0, stream>>>(
      qkvbuf, WoT, bo, d_out, BS * SL, NE, NE, N3);
}